// Round 10
// baseline (185.834 us; speedup 1.0000x reference)
//
#include <hip/hip_runtime.h>
#include <hip/hip_bf16.h>

#define DEVFN __device__ __forceinline__

typedef __bf16 bf16x8 __attribute__((ext_vector_type(8)));
typedef float f32x4 __attribute__((ext_vector_type(4)));
typedef float float4_t __attribute__((ext_vector_type(4)));
typedef unsigned short ushort8_t __attribute__((ext_vector_type(8)));
typedef unsigned short ushort4_t __attribute__((ext_vector_type(4)));
typedef unsigned int uint4_t __attribute__((ext_vector_type(4)));

constexpr int Bd = 8, Cd = 512, Nd = 4096, Dd = 64;

DEVFN unsigned short f2bf(float f) {
    union { float f; unsigned int u; } v; v.f = f;
    unsigned int r = (v.u + 0x7FFFu + ((v.u >> 16) & 1u)) >> 16;
    return (unsigned short)r;
}

DEVFN unsigned int pack2(float a, float b) {   // two f32 -> packed bf16x2 (RNE)
    __hip_bfloat162 h = __float22bfloat162_rn(make_float2(a, b));
    union { __hip_bfloat162 h; unsigned int u; } c; c.h = h;
    return c.u;
}

DEVFN bf16x8 ld_bf8(const unsigned short* p) {
    ushort8_t u = *(const ushort8_t*)p;
    return __builtin_bit_cast(bf16x8, u);
}

DEVFN f32x4 mfma16(bf16x8 a, bf16x8 b, f32x4 c) {
    return __builtin_amdgcn_mfma_f32_16x16x32_bf16(a, b, c, 0, 0, 0);
}

// ---------------- K0: convert weights to bf16 ----------------
__global__ __launch_bounds__(256) void k_cvtw(
    const float* __restrict__ Wq, const float* __restrict__ Wk,
    const float* __restrict__ Wv, const float* __restrict__ Wo,
    unsigned short* __restrict__ w4)
{
    int i = blockIdx.x * 256 + threadIdx.x;   // 0..32767
    w4[i]          = f2bf(Wq[i]);
    w4[32768 + i]  = f2bf(Wk[i]);
    w4[65536 + i]  = f2bf(Wv[i]);
    w4[98304 + i]  = f2bf(Wo[i]);
}

// ---------------- K1 v5: QKV, single-wave blocks, ZERO barriers ----------------
// Wave = 16 n-rows x one matrix (q|k|v per blockIdx.z). Grid 256x8x3 = 6144 waves.
// x staged wave-privately: lane l owns c-row c0+l, reads its 64B sector (4 float4),
// transposes into LDS [16n][72c-pad] via 16 ds_write_b16 (conflict-free). In-order
// DS within a wave + compile-time fences replace __syncthreads -> no vmcnt(0)
// drain (round-9 lesson: every s_barrier force-drains all outstanding loads).
// 2-deep named-reg pipeline (A/B) gives each x-load ~2 compute phases of cover.
__global__ __launch_bounds__(64, 4) void k_qkv(
    const float* __restrict__ x,
    const unsigned short* __restrict__ w4,
    const float* __restrict__ bq, const float* __restrict__ bk, const float* __restrict__ bv,
    unsigned short* __restrict__ q_nd, unsigned short* __restrict__ k_nd,
    unsigned short* __restrict__ v_dn)
{
    const int n0w = blockIdx.x * 16;
    const int b   = blockIdx.y;
    const int mat = blockIdx.z;
    const int l   = threadIdx.x, lo = l & 15, hi = l >> 4;
    const unsigned short* wm = w4 + mat * 32768;
    const float* bias = (mat == 0) ? bq : (mat == 1) ? bk : bv;
    const float* xb = x + (size_t)b * Cd * Nd + n0w;

    __shared__ __align__(16) unsigned short sm[64 * 24];  // xt view [16][72]; v-epi view [64][24]

    f32x4 acc[4] = {};
    float4_t xsA[4], xsB[4];

    auto gloadA = [&](int t) {
        const float* p = xb + (size_t)(t * 64 + l) * Nd;
        #pragma unroll
        for (int i = 0; i < 4; ++i) xsA[i] = *(const float4_t*)(p + i * 4);
    };
    auto gloadB = [&](int t) {
        const float* p = xb + (size_t)(t * 64 + l) * Nd;
        #pragma unroll
        for (int i = 0; i < 4; ++i) xsB[i] = *(const float4_t*)(p + i * 4);
    };
    auto dswriteA = [&]() {     // transpose: sm[n-local i][c-local l]
        #pragma unroll
        for (int i = 0; i < 16; ++i)
            sm[i * 72 + l] = f2bf(xsA[i >> 2][i & 3]);
    };
    auto dswriteB = [&]() {
        #pragma unroll
        for (int i = 0; i < 16; ++i)
            sm[i * 72 + l] = f2bf(xsB[i >> 2][i & 3]);
    };
    auto compute = [&](int t) {
        #pragma unroll
        for (int kk = 0; kk < 2; ++kk) {
            bf16x8 af = ld_bf8(&sm[lo * 72 + kk * 32 + hi * 8]);
            #pragma unroll
            for (int j = 0; j < 4; ++j) {
                bf16x8 bf = ld_bf8(wm + (j * 16 + lo) * Cd + t * 64 + kk * 32 + hi * 8);
                acc[j] = mfma16(af, bf, acc[j]);
            }
        }
    };

    gloadA(0);
    gloadB(1);
    for (int t = 0; t < 8; t += 2) {
        dswriteA();                              // tile t into LDS (waits only its own regs)
        asm volatile("" ::: "memory");
        if (t + 2 < 8) gloadA(t + 2);            // refill A; ~2 compute phases of cover
        __builtin_amdgcn_sched_barrier(0);
        compute(t);
        asm volatile("" ::: "memory");           // reads before next overwrite (in-order DS)
        dswriteB();                              // tile t+1
        asm volatile("" ::: "memory");
        if (t + 3 < 8) gloadB(t + 3);
        __builtin_amdgcn_sched_barrier(0);
        compute(t + 1);
        asm volatile("" ::: "memory");
    }

    // ---- epilogue (wave-private LDS transpose, round-8 proven) ----
    if (mat < 2) {
        #pragma unroll
        for (int j = 0; j < 4; ++j) {
            const float bia = bias[j * 16 + lo];
            #pragma unroll
            for (int r = 0; r < 4; ++r)
                sm[(hi * 4 + r) * 72 + j * 16 + lo] = f2bf(acc[j][r] + bia);
        }
        asm volatile("" ::: "memory");
        const int row = l >> 2, dg = l & 3;
        ushort8_t a0 = *(const ushort8_t*)&sm[row * 72 + dg * 16];
        ushort8_t a1 = *(const ushort8_t*)&sm[row * 72 + dg * 16 + 8];
        unsigned short* dst = (mat ? k_nd : q_nd)
            + ((size_t)b * Nd + n0w + row) * 64 + dg * 16;
        *(ushort8_t*)dst = a0; *(ushort8_t*)(dst + 8) = a1;
    } else {
        #pragma unroll
        for (int j = 0; j < 4; ++j) {
            const float bia = bias[j * 16 + lo];
            #pragma unroll
            for (int r = 0; r < 4; ++r)
                sm[(j * 16 + lo) * 24 + hi * 4 + r] = f2bf(acc[j][r] + bia);
        }
        asm volatile("" ::: "memory");
        ushort8_t a0 = *(const ushort8_t*)&sm[l * 24];
        ushort8_t a1 = *(const ushort8_t*)&sm[l * 24 + 8];
        unsigned short* dst = v_dn + ((size_t)b * Dd + l) * Nd + n0w;
        *(ushort8_t*)dst = a0; *(ushort8_t*)(dst + 8) = a1;
    }
}

// ---------------- K2 v3: flash attention, 32q blocks, LDS overlay, 4 blocks/CU ----------------
// Wave (qh, kh): 16 q-rows x 32 keys per 64-key tile. Same P/pi machinery as the
// validated round-6 kernel, with the qs loop removed. red_* overlays the dead
// K/V tiles after the loop -> LDS 32 KB -> 4 blocks/CU.
__global__ __launch_bounds__(256, 4) void k_attn(
    const unsigned short* __restrict__ q_nd,
    const unsigned short* __restrict__ k_nd,
    const unsigned short* __restrict__ v_dn,
    unsigned short* __restrict__ o_nd)
{
    const int bid = blockIdx.x;
    const int b   = bid & 7;            // round-robin XCD dispatch -> batch-per-XCD L2 locality
    const int n0  = (bid >> 3) * 32;
    const int tid = threadIdx.x, wid = tid >> 6, l = tid & 63;
    const int lo  = l & 15, hi = l >> 4;
    const int lsw = lo & 7;
    const int qh  = wid >> 1;           // q-subtile (16 rows)
    const int kh  = wid & 1;            // key-half (32 keys)
    const int wk0 = kh * 32;

    __shared__ unsigned short k_tiles[2][64 * 64];
    __shared__ unsigned short v_tiles[2][64 * 64];
    float* red_acc = (float*)&k_tiles[0][0];    // [2 qh][4 ds][256] = 8 KB (tiles dead)
    float* red_l   = (float*)&v_tiles[0][0];    // [2 qh][16]

    const unsigned short* qb = q_nd + (size_t)b * Nd * Dd;
    const unsigned short* kb = k_nd + (size_t)b * Nd * Dd;
    const unsigned short* vb = v_dn + (size_t)b * Dd * Nd;

    bf16x8 aq[2];
    #pragma unroll
    for (int kc = 0; kc < 2; ++kc)
        aq[kc] = ld_bf8(qb + (size_t)(n0 + qh*16 + lo) * 64 + kc*32 + hi*8);

    f32x4 acc[4] = {};
    float l_p = 0.f;

    const int sr = tid >> 3, ss = tid & 7;
    const int kwsl = (ss ^ (sr & 7)) * 8;
    const int vkh = ss >> 2, vsl = ss & 3, vms = vsl >> 1;
    const int vg0 = vkh * 4 + ((2 * vsl) & 3);
    const int vg1 = vkh * 4 + ((2 * vsl + 1) & 3);
    const int vsw = sr & 7;
    ushort8_t kr0, kr1, vr0, vr1;

    auto gload = [&](int t) {
        const size_t m1 = (size_t)t * 64;
        kr0 = *(const ushort8_t*)(kb + (m1 + sr) * 64 + ss * 8);
        kr1 = *(const ushort8_t*)(kb + (m1 + 32 + sr) * 64 + ss * 8);
        vr0 = *(const ushort8_t*)(vb + (size_t)sr * Nd + m1 + ss * 8);
        vr1 = *(const ushort8_t*)(vb + (size_t)(32 + sr) * Nd + m1 + ss * 8);
    };
    auto dswrite = [&](int buf) {
        unsigned short* kt = k_tiles[buf];
        unsigned short* vt = v_tiles[buf];
        *(ushort8_t*)(kt + sr * 64 + kwsl)        = kr0;
        *(ushort8_t*)(kt + (32 + sr) * 64 + kwsl) = kr1;
        ushort4_t a0 = __builtin_shufflevector(vr0, vr0, 0, 1, 2, 3);
        ushort4_t a1 = __builtin_shufflevector(vr0, vr0, 4, 5, 6, 7);
        ushort4_t b0 = __builtin_shufflevector(vr1, vr1, 0, 1, 2, 3);
        ushort4_t b1 = __builtin_shufflevector(vr1, vr1, 4, 5, 6, 7);
        *(ushort4_t*)(vt + sr * 64 + (vg0 ^ vsw) * 8 + vms * 4)        = a0;
        *(ushort4_t*)(vt + sr * 64 + (vg1 ^ vsw) * 8 + vms * 4)        = a1;
        *(ushort4_t*)(vt + (32 + sr) * 64 + (vg0 ^ vsw) * 8 + vms * 4) = b0;
        *(ushort4_t*)(vt + (32 + sr) * 64 + (vg1 ^ vsw) * 8 + vms * 4) = b1;
    };

    auto compute = [&](int buf) {
        const unsigned short* kt = k_tiles[buf];
        const unsigned short* vt = v_tiles[buf];
        f32x4 s[2] = {};
        #pragma unroll
        for (int ms = 0; ms < 2; ++ms) {
            #pragma unroll
            for (int kc = 0; kc < 2; ++kc) {
                bf16x8 kf = ld_bf8(kt + (wk0 + ms*16 + lo) * 64 + (((kc*4 + hi) ^ lsw) * 8));
                s[ms] = mfma16(kf, aq[kc], s[ms]);
            }
        }
        bf16x8 vf[4];
        #pragma unroll
        for (int ds = 0; ds < 4; ++ds)
            vf[ds] = ld_bf8(vt + (ds*16 + lo) * 64 + (((kh*4 + hi) ^ lsw) * 8));
        float p[2][4];
        #pragma unroll
        for (int ms = 0; ms < 2; ++ms)
            #pragma unroll
            for (int r = 0; r < 4; ++r)
                p[ms][r] = __expf(s[ms][r]);
        l_p += ((p[0][0] + p[0][1]) + (p[0][2] + p[0][3]))
             + ((p[1][0] + p[1][1]) + (p[1][2] + p[1][3]));
        uint4_t w;
        w[0] = pack2(p[0][0], p[0][1]);
        w[1] = pack2(p[0][2], p[0][3]);
        w[2] = pack2(p[1][0], p[1][1]);
        w[3] = pack2(p[1][2], p[1][3]);
        bf16x8 apf = __builtin_bit_cast(bf16x8, w);
        #pragma unroll
        for (int ds = 0; ds < 4; ++ds)
            acc[ds] = mfma16(apf, vf[ds], acc[ds]);
    };

    constexpr int NT = Nd / 64;
    gload(0);
    dswrite(0);
    __syncthreads();
    for (int t = 0; t < NT; ++t) {
        const int cur = t & 1;
        if (t + 1 < NT) gload(t + 1);
        __builtin_amdgcn_sched_barrier(0);
        compute(cur);
        if (t + 1 < NT) dswrite(cur ^ 1);
        __syncthreads();
    }

    // ---- epilogue: cross-kh reduce via LDS overlay, normalize, store ----
    float lh = l_p;
    lh += __shfl_xor(lh, 16, 64);
    lh += __shfl_xor(lh, 32, 64);               // sum over this wave's 32 keys, q = base+lo
    if (kh == 1) {
        #pragma unroll
        for (int ds = 0; ds < 4; ++ds)
            *(f32x4*)&red_acc[(qh * 4 + ds) * 256 + l * 4] = acc[ds];
        red_l[qh * 16 + lo] = lh;
    }
    __syncthreads();
    if (kh == 0) {
        #pragma unroll
        for (int ds = 0; ds < 4; ++ds)
            acc[ds] += *(const f32x4*)&red_acc[(qh * 4 + ds) * 256 + l * 4];
        float l_tot = lh + red_l[qh * 16 + lo];
        #pragma unroll
        for (int r = 0; r < 4; ++r) {
            float lq = __shfl(l_tot, hi * 4 + r, 16);
            float rl = 1.0f / lq;
            #pragma unroll
            for (int ds = 0; ds < 4; ++ds) {
                float o = acc[ds][r] * rl;
                o_nd[((size_t)b * Nd + n0 + qh*16 + hi*4 + r) * 64 + ds*16 + lo] = f2bf(o);
            }
        }
    }
}

// ---------------- K3: output projection + residual ----------------
__global__ __launch_bounds__(256) void k_oproj(
    const unsigned short* __restrict__ o_nd,
    const unsigned short* __restrict__ wo,
    const float* __restrict__ bo,
    const float* __restrict__ gamma,
    const float* __restrict__ x,
    float* __restrict__ out)
{
    const int b   = blockIdx.y;
    const int n0  = blockIdx.x * 64;
    const int tid = threadIdx.x, wid = tid >> 6, l = tid & 63;
    const int lo  = l & 15, hi = l >> 4;
    const int n0w = n0 + wid * 16;
    const float g = gamma[0];

    bf16x8 ao[2];
    #pragma unroll
    for (int kc = 0; kc < 2; ++kc)
        ao[kc] = ld_bf8(o_nd + ((size_t)b * Nd + n0w + lo) * 64 + kc*32 + hi*8);

    for (int ct = 0; ct < 32; ++ct) {
        f32x4 acc = {};
        #pragma unroll
        for (int kc = 0; kc < 2; ++kc) {
            bf16x8 bw = ld_bf8(wo + (ct*16 + lo) * 64 + kc*32 + hi*8);
            acc = mfma16(ao[kc], bw, acc);
        }
        const int c = ct*16 + lo;
        const float bc = bo[c];
        const size_t base = ((size_t)b * Cd + c) * Nd + n0w + hi*4;
        float4_t xv = *(const float4_t*)(x + base);
        float4_t ov;
        #pragma unroll
        for (int r = 0; r < 4; ++r) ov[r] = g * (acc[r] + bc) + xv[r];
        *(float4_t*)(out + base) = ov;
    }
}

extern "C" void kernel_launch(void* const* d_in, const int* in_sizes, int n_in,
                              void* d_out, int out_size, void* d_ws, size_t ws_size,
                              hipStream_t stream) {
    (void)in_sizes; (void)n_in; (void)out_size; (void)ws_size;
    const float* x  = (const float*)d_in[0];
    const float* Wq = (const float*)d_in[1];
    const float* bq = (const float*)d_in[2];
    const float* Wk = (const float*)d_in[3];
    const float* bk = (const float*)d_in[4];
    const float* Wv = (const float*)d_in[5];
    const float* bv = (const float*)d_in[6];
    const float* Wo = (const float*)d_in[7];
    const float* bo = (const float*)d_in[8];
    const float* gm = (const float*)d_in[9];
    float* out = (float*)d_out;

    unsigned short* w4   = (unsigned short*)d_ws;          // 4 x 32768 bf16 weights
    unsigned short* q_nd = w4 + 131072;
    unsigned short* k_nd = q_nd + (size_t)Bd * Nd * Dd;
    unsigned short* v_dn = k_nd + (size_t)Bd * Nd * Dd;
    unsigned short* o_nd = v_dn + (size_t)Bd * Nd * Dd;

    k_cvtw<<<128, 256, 0, stream>>>(Wq, Wk, Wv, Wo, w4);
    dim3 gq(Nd / 16, Bd, 3);
    k_qkv<<<gq, 64, 0, stream>>>(x, w4, bq, bk, bv, q_nd, k_nd, v_dn);
    k_attn<<<1024, 256, 0, stream>>>(q_nd, k_nd, v_dn, o_nd);
    dim3 g1(Nd / 64, Bd);
    k_oproj<<<g1, 256, 0, stream>>>(o_nd, w4 + 98304, bo, gm, x, out);
}

// Round 11
// 166.535 us; speedup vs baseline: 1.1159x; 1.1159x over previous
//
#include <hip/hip_runtime.h>
#include <hip/hip_bf16.h>

#define DEVFN __device__ __forceinline__

typedef __bf16 bf16x8 __attribute__((ext_vector_type(8)));
typedef float f32x4 __attribute__((ext_vector_type(4)));
typedef float float4_t __attribute__((ext_vector_type(4)));
typedef unsigned short ushort8_t __attribute__((ext_vector_type(8)));
typedef unsigned short ushort4_t __attribute__((ext_vector_type(4)));
typedef unsigned int uint4_t __attribute__((ext_vector_type(4)));

constexpr int Bd = 8, Cd = 512, Nd = 4096, Dd = 64;

DEVFN unsigned short f2bf(float f) {
    union { float f; unsigned int u; } v; v.f = f;
    unsigned int r = (v.u + 0x7FFFu + ((v.u >> 16) & 1u)) >> 16;
    return (unsigned short)r;
}

DEVFN unsigned int pack2(float a, float b) {   // two f32 -> packed bf16x2 (RNE)
    __hip_bfloat162 h = __float22bfloat162_rn(make_float2(a, b));
    union { __hip_bfloat162 h; unsigned int u; } c; c.h = h;
    return c.u;
}

DEVFN bf16x8 ld_bf8(const unsigned short* p) {
    ushort8_t u = *(const ushort8_t*)p;
    return __builtin_bit_cast(bf16x8, u);
}

DEVFN f32x4 mfma16(bf16x8 a, bf16x8 b, f32x4 c) {
    return __builtin_amdgcn_mfma_f32_16x16x32_bf16(a, b, c, 0, 0, 0);
}

// ---------------- K0: convert weights to bf16 ----------------
__global__ __launch_bounds__(256) void k_cvtw(
    const float* __restrict__ Wq, const float* __restrict__ Wk,
    const float* __restrict__ Wv, const float* __restrict__ Wo,
    unsigned short* __restrict__ w4)
{
    int i = blockIdx.x * 256 + threadIdx.x;   // 0..32767
    w4[i]          = f2bf(Wq[i]);
    w4[32768 + i]  = f2bf(Wk[i]);
    w4[65536 + i]  = f2bf(Wv[i]);
    w4[98304 + i]  = f2bf(Wo[i]);
}

// ---------------- K1 v6: QKV, single-wave blocks, zero barriers, ALL 12 d-tiles/wave ----
// Wave = 16 n-rows x {q,k,v} (x staged ONCE -> no round-10 3x fetch). Grid 256x8.
// Lane l owns c-row c0+l: reads its 64B sector (4 float4), transposes into
// wave-private LDS [16n][72c]; in-order DS + compile-time fences, no s_barrier
// -> no forced vmcnt(0) drain (round-9/10 lesson). 2-deep named-reg pipeline.
__global__ __launch_bounds__(64, 2) void k_qkv(
    const float* __restrict__ x,
    const unsigned short* __restrict__ w4,
    const float* __restrict__ bq, const float* __restrict__ bk, const float* __restrict__ bv,
    unsigned short* __restrict__ q_nd, unsigned short* __restrict__ k_nd,
    unsigned short* __restrict__ v_dn)
{
    const int n0w = blockIdx.x * 16;
    const int b   = blockIdx.y;
    const int l   = threadIdx.x, lo = l & 15, hi = l >> 4;
    const float* xb = x + (size_t)b * Cd * Nd + n0w;

    __shared__ __align__(16) unsigned short sm[64 * 24];  // xt view [16][72]; v-epi view [64][24]

    f32x4 acc[12] = {};
    float4_t xsA[4], xsB[4];

    auto gloadA = [&](int t) {
        const float* p = xb + (size_t)(t * 64 + l) * Nd;
        #pragma unroll
        for (int i = 0; i < 4; ++i) xsA[i] = *(const float4_t*)(p + i * 4);
    };
    auto gloadB = [&](int t) {
        const float* p = xb + (size_t)(t * 64 + l) * Nd;
        #pragma unroll
        for (int i = 0; i < 4; ++i) xsB[i] = *(const float4_t*)(p + i * 4);
    };
    auto dswriteA = [&]() {     // transpose: sm[n-local i][c-local l]
        #pragma unroll
        for (int i = 0; i < 16; ++i)
            sm[i * 72 + l] = f2bf(xsA[i >> 2][i & 3]);
    };
    auto dswriteB = [&]() {
        #pragma unroll
        for (int i = 0; i < 16; ++i)
            sm[i * 72 + l] = f2bf(xsB[i >> 2][i & 3]);
    };
    auto compute = [&](int t) {
        #pragma unroll
        for (int kk = 0; kk < 2; ++kk) {
            bf16x8 af = ld_bf8(&sm[lo * 72 + kk * 32 + hi * 8]);
            #pragma unroll
            for (int j = 0; j < 12; ++j) {
                const unsigned short* wm = w4 + (j >> 2) * 32768;
                bf16x8 bf = ld_bf8(wm + ((j & 3) * 16 + lo) * Cd + t * 64 + kk * 32 + hi * 8);
                acc[j] = mfma16(af, bf, acc[j]);
            }
        }
    };

    gloadA(0);
    gloadB(1);
    for (int t = 0; t < 8; t += 2) {
        dswriteA();                              // tile t into LDS (waits only its own regs)
        asm volatile("" ::: "memory");
        if (t + 2 < 8) gloadA(t + 2);            // refill A; ~2 compute phases of cover
        __builtin_amdgcn_sched_barrier(0);
        compute(t);
        asm volatile("" ::: "memory");           // reads before overwrite (in-order DS)
        dswriteB();                              // tile t+1
        asm volatile("" ::: "memory");
        if (t + 3 < 8) gloadB(t + 3);
        __builtin_amdgcn_sched_barrier(0);
        compute(t + 1);
        asm volatile("" ::: "memory");
    }

    // ---- epilogue: q, k via per-wave LDS transpose (validated pattern) ----
    #pragma unroll
    for (int m = 0; m < 2; ++m) {
        const float* bias = m ? bk : bq;
        #pragma unroll
        for (int j = 0; j < 4; ++j) {
            const float bia = bias[j * 16 + lo];
            #pragma unroll
            for (int r = 0; r < 4; ++r)
                sm[(hi * 4 + r) * 72 + j * 16 + lo] = f2bf(acc[m * 4 + j][r] + bia);
        }
        asm volatile("" ::: "memory");
        const int row = l >> 2, dg = l & 3;
        ushort8_t a0 = *(const ushort8_t*)&sm[row * 72 + dg * 16];
        ushort8_t a1 = *(const ushort8_t*)&sm[row * 72 + dg * 16 + 8];
        unsigned short* dst = (m ? k_nd : q_nd)
            + ((size_t)b * Nd + n0w + row) * 64 + dg * 16;
        *(ushort8_t*)dst = a0; *(ushort8_t*)(dst + 8) = a1;
        asm volatile("" ::: "memory");           // m=0 reads before m=1 overwrites
    }

    // ---- epilogue: v via [64d][24] transpose, 32B d-row stores ----
    #pragma unroll
    for (int j = 0; j < 4; ++j) {
        const float bia = bv[j * 16 + lo];
        #pragma unroll
        for (int r = 0; r < 4; ++r)
            sm[(j * 16 + lo) * 24 + hi * 4 + r] = f2bf(acc[8 + j][r] + bia);
    }
    asm volatile("" ::: "memory");
    {
        ushort8_t a0 = *(const ushort8_t*)&sm[l * 24];
        ushort8_t a1 = *(const ushort8_t*)&sm[l * 24 + 8];
        unsigned short* dst = v_dn + ((size_t)b * Dd + l) * Nd + n0w;
        *(ushort8_t*)dst = a0; *(ushort8_t*)(dst + 8) = a1;
    }
}

// ---------------- K2 v3: flash attention, 32q blocks, LDS overlay, 4 blocks/CU ----------------
// (unchanged from round 10)
__global__ __launch_bounds__(256, 4) void k_attn(
    const unsigned short* __restrict__ q_nd,
    const unsigned short* __restrict__ k_nd,
    const unsigned short* __restrict__ v_dn,
    unsigned short* __restrict__ o_nd)
{
    const int bid = blockIdx.x;
    const int b   = bid & 7;            // round-robin XCD dispatch -> batch-per-XCD L2 locality
    const int n0  = (bid >> 3) * 32;
    const int tid = threadIdx.x, wid = tid >> 6, l = tid & 63;
    const int lo  = l & 15, hi = l >> 4;
    const int lsw = lo & 7;
    const int qh  = wid >> 1;           // q-subtile (16 rows)
    const int kh  = wid & 1;            // key-half (32 keys)
    const int wk0 = kh * 32;

    __shared__ unsigned short k_tiles[2][64 * 64];
    __shared__ unsigned short v_tiles[2][64 * 64];
    float* red_acc = (float*)&k_tiles[0][0];    // [2 qh][4 ds][256] = 8 KB (tiles dead)
    float* red_l   = (float*)&v_tiles[0][0];    // [2 qh][16]

    const unsigned short* qb = q_nd + (size_t)b * Nd * Dd;
    const unsigned short* kb = k_nd + (size_t)b * Nd * Dd;
    const unsigned short* vb = v_dn + (size_t)b * Dd * Nd;

    bf16x8 aq[2];
    #pragma unroll
    for (int kc = 0; kc < 2; ++kc)
        aq[kc] = ld_bf8(qb + (size_t)(n0 + qh*16 + lo) * 64 + kc*32 + hi*8);

    f32x4 acc[4] = {};
    float l_p = 0.f;

    const int sr = tid >> 3, ss = tid & 7;
    const int kwsl = (ss ^ (sr & 7)) * 8;
    const int vkh = ss >> 2, vsl = ss & 3, vms = vsl >> 1;
    const int vg0 = vkh * 4 + ((2 * vsl) & 3);
    const int vg1 = vkh * 4 + ((2 * vsl + 1) & 3);
    const int vsw = sr & 7;
    ushort8_t kr0, kr1, vr0, vr1;

    auto gload = [&](int t) {
        const size_t m1 = (size_t)t * 64;
        kr0 = *(const ushort8_t*)(kb + (m1 + sr) * 64 + ss * 8);
        kr1 = *(const ushort8_t*)(kb + (m1 + 32 + sr) * 64 + ss * 8);
        vr0 = *(const ushort8_t*)(vb + (size_t)sr * Nd + m1 + ss * 8);
        vr1 = *(const ushort8_t*)(vb + (size_t)(32 + sr) * Nd + m1 + ss * 8);
    };
    auto dswrite = [&](int buf) {
        unsigned short* kt = k_tiles[buf];
        unsigned short* vt = v_tiles[buf];
        *(ushort8_t*)(kt + sr * 64 + kwsl)        = kr0;
        *(ushort8_t*)(kt + (32 + sr) * 64 + kwsl) = kr1;
        ushort4_t a0 = __builtin_shufflevector(vr0, vr0, 0, 1, 2, 3);
        ushort4_t a1 = __builtin_shufflevector(vr0, vr0, 4, 5, 6, 7);
        ushort4_t b0 = __builtin_shufflevector(vr1, vr1, 0, 1, 2, 3);
        ushort4_t b1 = __builtin_shufflevector(vr1, vr1, 4, 5, 6, 7);
        *(ushort4_t*)(vt + sr * 64 + (vg0 ^ vsw) * 8 + vms * 4)        = a0;
        *(ushort4_t*)(vt + sr * 64 + (vg1 ^ vsw) * 8 + vms * 4)        = a1;
        *(ushort4_t*)(vt + (32 + sr) * 64 + (vg0 ^ vsw) * 8 + vms * 4) = b0;
        *(ushort4_t*)(vt + (32 + sr) * 64 + (vg1 ^ vsw) * 8 + vms * 4) = b1;
    };

    auto compute = [&](int buf) {
        const unsigned short* kt = k_tiles[buf];
        const unsigned short* vt = v_tiles[buf];
        f32x4 s[2] = {};
        #pragma unroll
        for (int ms = 0; ms < 2; ++ms) {
            #pragma unroll
            for (int kc = 0; kc < 2; ++kc) {
                bf16x8 kf = ld_bf8(kt + (wk0 + ms*16 + lo) * 64 + (((kc*4 + hi) ^ lsw) * 8));
                s[ms] = mfma16(kf, aq[kc], s[ms]);
            }
        }
        bf16x8 vf[4];
        #pragma unroll
        for (int ds = 0; ds < 4; ++ds)
            vf[ds] = ld_bf8(vt + (ds*16 + lo) * 64 + (((kh*4 + hi) ^ lsw) * 8));
        float p[2][4];
        #pragma unroll
        for (int ms = 0; ms < 2; ++ms)
            #pragma unroll
            for (int r = 0; r < 4; ++r)
                p[ms][r] = __expf(s[ms][r]);
        l_p += ((p[0][0] + p[0][1]) + (p[0][2] + p[0][3]))
             + ((p[1][0] + p[1][1]) + (p[1][2] + p[1][3]));
        uint4_t w;
        w[0] = pack2(p[0][0], p[0][1]);
        w[1] = pack2(p[0][2], p[0][3]);
        w[2] = pack2(p[1][0], p[1][1]);
        w[3] = pack2(p[1][2], p[1][3]);
        bf16x8 apf = __builtin_bit_cast(bf16x8, w);
        #pragma unroll
        for (int ds = 0; ds < 4; ++ds)
            acc[ds] = mfma16(apf, vf[ds], acc[ds]);
    };

    constexpr int NT = Nd / 64;
    gload(0);
    dswrite(0);
    __syncthreads();
    for (int t = 0; t < NT; ++t) {
        const int cur = t & 1;
        if (t + 1 < NT) gload(t + 1);
        __builtin_amdgcn_sched_barrier(0);
        compute(cur);
        if (t + 1 < NT) dswrite(cur ^ 1);
        __syncthreads();
    }

    // ---- epilogue: cross-kh reduce via LDS overlay, normalize, store ----
    float lh = l_p;
    lh += __shfl_xor(lh, 16, 64);
    lh += __shfl_xor(lh, 32, 64);               // sum over this wave's 32 keys, q = base+lo
    if (kh == 1) {
        #pragma unroll
        for (int ds = 0; ds < 4; ++ds)
            *(f32x4*)&red_acc[(qh * 4 + ds) * 256 + l * 4] = acc[ds];
        red_l[qh * 16 + lo] = lh;
    }
    __syncthreads();
    if (kh == 0) {
        #pragma unroll
        for (int ds = 0; ds < 4; ++ds)
            acc[ds] += *(const f32x4*)&red_acc[(qh * 4 + ds) * 256 + l * 4];
        float l_tot = lh + red_l[qh * 16 + lo];
        #pragma unroll
        for (int r = 0; r < 4; ++r) {
            float lq = __shfl(l_tot, hi * 4 + r, 16);
            float rl = 1.0f / lq;
            #pragma unroll
            for (int ds = 0; ds < 4; ++ds) {
                float o = acc[ds][r] * rl;
                o_nd[((size_t)b * Nd + n0 + qh*16 + hi*4 + r) * 64 + ds*16 + lo] = f2bf(o);
            }
        }
    }
}

// ---------------- K3: output projection + residual ----------------
__global__ __launch_bounds__(256) void k_oproj(
    const unsigned short* __restrict__ o_nd,
    const unsigned short* __restrict__ wo,
    const float* __restrict__ bo,
    const float* __restrict__ gamma,
    const float* __restrict__ x,
    float* __restrict__ out)
{
    const int b   = blockIdx.y;
    const int n0  = blockIdx.x * 64;
    const int tid = threadIdx.x, wid = tid >> 6, l = tid & 63;
    const int lo  = l & 15, hi = l >> 4;
    const int n0w = n0 + wid * 16;
    const float g = gamma[0];

    bf16x8 ao[2];
    #pragma unroll
    for (int kc = 0; kc < 2; ++kc)
        ao[kc] = ld_bf8(o_nd + ((size_t)b * Nd + n0w + lo) * 64 + kc*32 + hi*8);

    for (int ct = 0; ct < 32; ++ct) {
        f32x4 acc = {};
        #pragma unroll
        for (int kc = 0; kc < 2; ++kc) {
            bf16x8 bw = ld_bf8(wo + (ct*16 + lo) * 64 + kc*32 + hi*8);
            acc = mfma16(ao[kc], bw, acc);
        }
        const int c = ct*16 + lo;
        const float bc = bo[c];
        const size_t base = ((size_t)b * Cd + c) * Nd + n0w + hi*4;
        float4_t xv = *(const float4_t*)(x + base);
        float4_t ov;
        #pragma unroll
        for (int r = 0; r < 4; ++r) ov[r] = g * (acc[r] + bc) + xv[r];
        *(float4_t*)(out + base) = ov;
    }
}

extern "C" void kernel_launch(void* const* d_in, const int* in_sizes, int n_in,
                              void* d_out, int out_size, void* d_ws, size_t ws_size,
                              hipStream_t stream) {
    (void)in_sizes; (void)n_in; (void)out_size; (void)ws_size;
    const float* x  = (const float*)d_in[0];
    const float* Wq = (const float*)d_in[1];
    const float* bq = (const float*)d_in[2];
    const float* Wk = (const float*)d_in[3];
    const float* bk = (const float*)d_in[4];
    const float* Wv = (const float*)d_in[5];
    const float* bv = (const float*)d_in[6];
    const float* Wo = (const float*)d_in[7];
    const float* bo = (const float*)d_in[8];
    const float* gm = (const float*)d_in[9];
    float* out = (float*)d_out;

    unsigned short* w4   = (unsigned short*)d_ws;          // 4 x 32768 bf16 weights
    unsigned short* q_nd = w4 + 131072;
    unsigned short* k_nd = q_nd + (size_t)Bd * Nd * Dd;
    unsigned short* v_dn = k_nd + (size_t)Bd * Nd * Dd;
    unsigned short* o_nd = v_dn + (size_t)Bd * Nd * Dd;

    k_cvtw<<<128, 256, 0, stream>>>(Wq, Wk, Wv, Wo, w4);
    dim3 gq(Nd / 16, Bd);
    k_qkv<<<gq, 64, 0, stream>>>(x, w4, bq, bk, bv, q_nd, k_nd, v_dn);
    k_attn<<<1024, 256, 0, stream>>>(q_nd, k_nd, v_dn, o_nd);
    dim3 g1(Nd / 64, Bd);
    k_oproj<<<g1, 256, 0, stream>>>(o_nd, w4 + 98304, bo, gm, x, out);
}